// Round 1
// baseline (590.819 us; speedup 1.0000x reference)
//
#include <hip/hip_runtime.h>

// NECBOW negative-sampling CBOW loss.
// Inputs (setup_inputs order):
//  0: windows  [B, 2W]  int32
//  1: centers  [B]      int32
//  2: num_sampled [1]   int32
//  3: embedding        [V, D]    f32
//  4: output_embedding [V, CTX]  f32
//  5: weights  [V]      f32
// Output: d_out[0] = loss (f32), d_out[1] = B (as f32)

#define TW        8      // 2*W window tokens
#define D_DIM     256
#define CTX_DIM   2048   // TW * D_DIM
#define F4_ROW    (CTX_DIM / 4)   // 512 float4 per output_embedding row
#define THREADS   256
#define MAX_ROWS  64     // 1 + NS upper bound

__device__ inline unsigned pcg_next(unsigned& state) {
    state = state * 747796405u + 2891336453u;
    unsigned word = ((state >> ((state >> 28u) + 4u)) ^ state) * 277803737u;
    return (word >> 22u) ^ word;
}

__global__ __launch_bounds__(THREADS) void necbow_main(
    const int*   __restrict__ windows,           // [B, TW]
    const int*   __restrict__ centers,           // [B]
    const int*   __restrict__ ns_ptr,            // [1]
    const float* __restrict__ embedding,         // [V, D_DIM]
    const float* __restrict__ output_embedding,  // [V, CTX_DIM]
    const float* __restrict__ weights,           // [V]
    float*       __restrict__ block_sums,        // [B]
    int V)
{
    __shared__ float4 ctx4[F4_ROW];      // 8 KB context tile
    __shared__ int    rows[MAX_ROWS];
    __shared__ float  wave_sums[4];

    const int b  = blockIdx.x;
    const int t  = threadIdx.x;
    const int NS = ns_ptr[0];

    // ---- stage context into LDS: 8 embedding rows -> 2048 floats ----
    const float4* emb4 = (const float4*)embedding;   // 64 float4 per row
    #pragma unroll
    for (int i = 0; i < 2; ++i) {
        int g   = t + i * THREADS;       // 0..511
        int j   = g >> 6;                // which window token (0..7)
        int col = g & 63;                // float4 column within row
        int row = windows[b * TW + j];
        ctx4[g] = emb4[(size_t)row * 64 + col];
    }

    // ---- sample rows: rows[0]=center, rows[1..NS]=weighted negatives ----
    if (t == 0) rows[0] = centers[b];
    if (t >= 1 && t <= NS && t < MAX_ROWS) {
        unsigned s = ((unsigned)b * 977u + (unsigned)t) * 0x9E3779B9u + 0x85EBCA6Bu;
        (void)pcg_next(s);
        int idx = 0;
        // rejection sampling: weights in (1e-3, ~1.001]; bound 1.0015
        for (int it = 0; it < 64; ++it) {
            unsigned r1 = pcg_next(s);
            unsigned r2 = pcg_next(s);
            idx = (int)(r1 % (unsigned)V);
            float u = (float)(r2 >> 8) * (1.0f / 16777216.0f);
            if (u * 1.0015f <= weights[idx]) break;
        }
        rows[t] = idx;
    }
    __syncthreads();

    // ---- 11 dot products, distributed across the 4 waves ----
    const int wave = t >> 6;
    const int lane = t & 63;
    const float4* oe4 = (const float4*)output_embedding;

    float wsum = 0.0f;
    for (int k = wave; k < 1 + NS; k += 4) {
        const float4* rp = oe4 + (size_t)rows[k] * F4_ROW;
        float dot = 0.0f;
        #pragma unroll
        for (int i = 0; i < F4_ROW / 64; ++i) {   // 8 float4 per lane
            float4 a = rp[lane + 64 * i];
            float4 c = ctx4[lane + 64 * i];
            dot += a.x * c.x + a.y * c.y + a.z * c.z + a.w * c.w;
        }
        #pragma unroll
        for (int off = 32; off > 0; off >>= 1)
            dot += __shfl_down(dot, off, 64);
        if (lane == 0) {
            float logit = (k == 0) ? dot : -dot;   // neg rows enter negated
            float z = -logit;                      // -log sigmoid(x) = softplus(-x)
            wsum += fmaxf(z, 0.0f) + log1pf(expf(-fabsf(z)));
        }
    }
    if (lane == 0) wave_sums[wave] = wsum;
    __syncthreads();
    if (t == 0)
        block_sums[b] = wave_sums[0] + wave_sums[1] + wave_sums[2] + wave_sums[3];
}

__global__ __launch_bounds__(THREADS) void necbow_reduce(
    const float* __restrict__ block_sums, int B, float* __restrict__ out)
{
    const int t = threadIdx.x;
    float s = 0.0f;
    for (int i = t; i < B; i += THREADS) s += block_sums[i];
    #pragma unroll
    for (int off = 32; off > 0; off >>= 1)
        s += __shfl_down(s, off, 64);
    __shared__ float ws[4];
    const int wave = t >> 6, lane = t & 63;
    if (lane == 0) ws[wave] = s;
    __syncthreads();
    if (t == 0) {
        out[0] = ws[0] + ws[1] + ws[2] + ws[3];
        out[1] = (float)B;   // centers.size
    }
}

extern "C" void kernel_launch(void* const* d_in, const int* in_sizes, int n_in,
                              void* d_out, int out_size, void* d_ws, size_t ws_size,
                              hipStream_t stream) {
    const int*   windows  = (const int*)d_in[0];
    const int*   centers  = (const int*)d_in[1];
    const int*   ns_ptr   = (const int*)d_in[2];
    const float* emb      = (const float*)d_in[3];
    const float* out_emb  = (const float*)d_in[4];
    const float* weights  = (const float*)d_in[5];

    const int B = in_sizes[1];
    const int V = in_sizes[5];

    float* block_sums = (float*)d_ws;   // B floats of scratch
    float* out        = (float*)d_out;

    necbow_main<<<B, THREADS, 0, stream>>>(windows, centers, ns_ptr, emb,
                                           out_emb, weights, block_sums, V);
    necbow_reduce<<<1, THREADS, 0, stream>>>(block_sums, B, out);
}